// Round 5
// baseline (1267.057 us; speedup 1.0000x reference)
//
#include <hip/hip_runtime.h>
#include <hip/hip_bf16.h>
#include <math.h>

typedef short s8v __attribute__((ext_vector_type(8)));
typedef float f32x4 __attribute__((ext_vector_type(4)));

__device__ __forceinline__ ushort f2bf(float f) {
    __hip_bfloat16 h = __float2bfloat16(f);
    return *reinterpret_cast<ushort*>(&h);
}
__device__ __forceinline__ float bf2f(ushort u) {
    return __uint_as_float(((unsigned)u) << 16);
}
__device__ __forceinline__ unsigned pack_split(float v) {
    ushort h = f2bf(v);
    ushort l = f2bf(v - bf2f(h));
    return ((unsigned)h << 16) | (unsigned)l;
}
__device__ __forceinline__ float unpack_f(unsigned p) {
    return __uint_as_float(p & 0xffff0000u) + __uint_as_float(p << 16);
}
__device__ __forceinline__ void gload16(const void* g, void* l) {
    __builtin_amdgcn_global_load_lds(
        (const __attribute__((address_space(1))) void*)g,
        (__attribute__((address_space(3))) void*)l, 16, 0, 0);
}
// from 8 packed u32 (k0..7) build hi-frag and lo-frag (8 bf16 each)
__device__ __forceinline__ void unpack8(const uint4 p0, const uint4 p1, s8v& hi, s8v& lo) {
    union { s8v v; unsigned u[4]; } H, L;
    H.u[0] = (p0.x >> 16) | (p0.y & 0xffff0000u);
    H.u[1] = (p0.z >> 16) | (p0.w & 0xffff0000u);
    H.u[2] = (p1.x >> 16) | (p1.y & 0xffff0000u);
    H.u[3] = (p1.z >> 16) | (p1.w & 0xffff0000u);
    L.u[0] = (p0.x & 0xffffu) | (p0.y << 16);
    L.u[1] = (p0.z & 0xffffu) | (p0.w << 16);
    L.u[2] = (p1.x & 0xffffu) | (p1.y << 16);
    L.u[3] = (p1.z & 0xffffu) | (p1.w << 16);
    hi = H.v; lo = L.v;
}

// ---------------- CSR build ----------------

__global__ __launch_bounds__(256)
void hist_kernel(const int* __restrict__ dst, int* __restrict__ cnt, int E) {
    int e = blockIdx.x * 256 + threadIdx.x;
    if (e < E) atomicAdd(&cnt[dst[e]], 1);
}

__global__ __launch_bounds__(1024)
void scan_kernel(const int* __restrict__ cnt, int* __restrict__ off, int n) {
    __shared__ int lds[1024];
    int t = threadIdx.x;
    int chunk = (n + 1023) >> 10;
    int begin = t * chunk;
    int end = min(begin + chunk, n);
    if (end < begin) end = begin;
    int s = 0;
    for (int i = begin; i < end; ++i) s += cnt[i];
    lds[t] = s;
    __syncthreads();
    for (int d = 1; d < 1024; d <<= 1) {
        int v = (t >= d) ? lds[t - d] : 0;
        __syncthreads();
        lds[t] += v;
        __syncthreads();
    }
    int pre = (t == 0) ? 0 : lds[t - 1];
    for (int i = begin; i < end; ++i) { off[i] = pre; pre += cnt[i]; }
    if (t == 1023) off[n] = pre;
}

__global__ __launch_bounds__(256)
void scatter_kernel(const int* __restrict__ src, const int* __restrict__ dst,
                    int* __restrict__ cur, const int* __restrict__ off,
                    int* __restrict__ csr, int E) {
    int e = blockIdx.x * 256 + threadIdx.x;
    if (e < E) {
        int d = dst[e];
        int pos = off[d] + atomicAdd(&cur[d], 1);
        csr[pos] = src[e];
    }
}

// ---------------- weight prep: transpose + hi/lo bf16 split planes ----------------

struct PrepArgs {
    const float* W[12];
    ushort* H[12];
    ushort* L[12];
    int end[12];
    int Kv[12];
    int nshift[12];
};

__global__ __launch_bounds__(256)
void prep_weights(PrepArgs a, int total) {
    int id = blockIdx.x * 256 + threadIdx.x;
    if (id >= total) return;
    int s = 0;
    #pragma unroll
    for (int i = 0; i < 12; ++i) if (id >= a.end[i]) s = i + 1;
    int base = (s == 0) ? 0 : a.end[s - 1];
    int e = id - base;
    int K = a.Kv[s];
    int Nmask = (1 << a.nshift[s]) - 1;
    int n = e & Nmask;
    int k = e >> a.nshift[s];
    float w = a.W[s][(size_t)k * (Nmask + 1) + n];
    ushort hi = f2bf(w);
    ushort lo = f2bf(w - bf2f(hi));
    a.H[s][(size_t)n * K + k] = hi;
    a.L[s][(size_t)n * K + k] = lo;
}

// ---------------- per-dst online-softmax aggregation (packed u32) ----------------

__global__ __launch_bounds__(256)
void sage_aggr_pk(const unsigned* __restrict__ X, const int* __restrict__ csr,
                  const int* __restrict__ off, unsigned* __restrict__ O, int nN) {
    int node = blockIdx.x * 4 + (threadIdx.x >> 6);
    if (node >= nN) return;
    int c4 = (threadIdx.x & 63) * 4;
    int s0 = off[node], s1 = off[node + 1];
    float m0 = -INFINITY, m1 = -INFINITY, m2 = -INFINITY, m3 = -INFINITY;
    float se0 = 0, se1 = 0, se2 = 0, se3 = 0;
    float sm0 = 0, sm1 = 0, sm2 = 0, sm3 = 0;
#define ONLSTEP(vv, mm, ss, pp) { float nm = fmaxf(mm, vv); float r = __expf(mm - nm); \
    float p = __expf(vv - nm); ss = ss * r + p; pp = pp * r + p * (vv); mm = nm; }
    for (int j = s0; j < s1; ++j) {
        uint4 p = *(const uint4*)(X + (size_t)csr[j] * 256 + c4);
        float v0 = unpack_f(p.x), v1 = unpack_f(p.y), v2 = unpack_f(p.z), v3 = unpack_f(p.w);
        ONLSTEP(v0, m0, se0, sm0) ONLSTEP(v1, m1, se1, sm1)
        ONLSTEP(v2, m2, se2, sm2) ONLSTEP(v3, m3, se3, sm3)
    }
#undef ONLSTEP
    uint4 o;
    o.x = pack_split((s1 > s0) ? sm0 / se0 : 0.f);
    o.y = pack_split((s1 > s0) ? sm1 / se1 : 0.f);
    o.z = pack_split((s1 > s0) ? sm2 / se2 : 0.f);
    o.w = pack_split((s1 > s0) ? sm3 / se3 : 0.f);
    *(uint4*)(O + (size_t)node * 256 + c4) = o;
}

// ---------------- fused GEMM chain kernel ----------------
// Block = 64 rows x full N (256). 4 waves, wave w owns cols [64w,64w+64).
// Per wave: 4x4 frags of 16x16, split-bf16 3-term MFMA, fp32 acc.
// Up to 3 chained GEMM stages; intermediates in LDS (packed u32 hi|lo).
// A sources: fp32 global (AFP32), packed global (1 or 2 = ATWO), or LDS x.
// B: pre-transposed [n][k] hi/lo weight planes, staged via global_load_lds.

template<int NST, int K0, bool AFP32, bool ATWO, int NLAST, bool DOTANH>
__global__ __launch_bounds__(256, (NST == 1) ? 2 : 1)
void chain_kernel(const float* __restrict__ Af,
                  const unsigned* __restrict__ Ap1, const unsigned* __restrict__ Ap2,
                  const ushort* __restrict__ W0H, const ushort* __restrict__ W0L,
                  const ushort* __restrict__ W0H2, const ushort* __restrict__ W0L2,
                  const ushort* __restrict__ W1H, const ushort* __restrict__ W1L,
                  const ushort* __restrict__ W2H, const ushort* __restrict__ W2L,
                  const float* __restrict__ bias0, const float* __restrict__ bias1,
                  const float* __restrict__ bias2,
                  unsigned* __restrict__ Cpk, float* __restrict__ Cf, int M) {
    // As: [2 buf][4 kg][2 half][64 row][16B]  = 16 KB  (A staging, packed u32 / split fp32)
    // Bs: [2 buf][2 pl][4 kg][256 n][16B]     = 64 KB  (B staging, separate hi/lo)
    __shared__ __align__(16) ushort As[2 * 4 * 2 * 64 * 8];
    __shared__ __align__(16) ushort Bs[2 * 2 * 4 * 256 * 8];

    const int tid = threadIdx.x;
    const int lane = tid & 63;
    const int w = tid >> 6;
    const int li = lane & 15, kq = lane >> 4;
    const int bm = blockIdx.x * 64;

    f32x4 acc[4][4];

    auto As_p = [&](int buf, int kg, int half, int row) -> ushort* {
        return As + (((buf * 4 + kg) * 2 + half) * 64 + row) * 8;
    };
    auto Bs_p = [&](int buf, int pl, int kg, int n) -> ushort* {
        return Bs + (((buf * 2 + pl) * 4 + kg) * 256 + n) * 8;
    };
    auto zero_acc = [&]() {
        #pragma unroll
        for (int i = 0; i < 4; ++i)
            #pragma unroll
            for (int j = 0; j < 4; ++j)
                acc[i][j] = (f32x4){0.f, 0.f, 0.f, 0.f};
    };
    auto stage_B = [&](const ushort* BH, const ushort* BL, int Ks, int k0, int buf, int Nsz) {
        int n = w * 64 + lane;
        if (n < Nsz) {
            const ushort* pH = BH + (size_t)n * Ks + k0;
            const ushort* pL = BL + (size_t)n * Ks + k0;
            #pragma unroll
            for (int kg = 0; kg < 4; ++kg) {
                gload16(pH + kg * 8, Bs_p(buf, 0, kg, n));
                gload16(pL + kg * 8, Bs_p(buf, 1, kg, n));
            }
        }
    };
    auto stage_A = [&](const unsigned* A, int k0, int buf) {
        // wave w stages kg=w, halves 0,1; lane = row
        #pragma unroll
        for (int s2 = 0; s2 < 2; ++s2) {
            const unsigned* src = A + (size_t)(bm + lane) * 256 + k0 + w * 8 + s2 * 4;
            gload16(src, As_p(buf, w, s2, lane));
        }
    };
    auto frags_A_As = [&](int buf, s8v* ah, s8v* al) {
        #pragma unroll
        for (int i = 0; i < 4; ++i) {
            uint4 p0 = *(const uint4*)(const void*)As_p(buf, kq, 0, 16 * i + li);
            uint4 p1 = *(const uint4*)(const void*)As_p(buf, kq, 1, 16 * i + li);
            unpack8(p0, p1, ah[i], al[i]);
        }
    };
    auto frags_B = [&](int buf, s8v* bh, s8v* bl) {
        #pragma unroll
        for (int i = 0; i < 4; ++i) {
            bh[i] = *(const s8v*)(const void*)Bs_p(buf, 0, kq, w * 64 + 16 * i + li);
            bl[i] = *(const s8v*)(const void*)Bs_p(buf, 1, kq, w * 64 + 16 * i + li);
        }
    };
    auto do_mfma = [&](s8v* ah, s8v* al, s8v* bh, s8v* bl) {
        #pragma unroll
        for (int i = 0; i < 4; ++i)
            #pragma unroll
            for (int j = 0; j < 4; ++j) {
                acc[i][j] = __builtin_amdgcn_mfma_f32_16x16x32_bf16(ah[i], bh[j], acc[i][j], 0, 0, 0);
                acc[i][j] = __builtin_amdgcn_mfma_f32_16x16x32_bf16(ah[i], bl[j], acc[i][j], 0, 0, 0);
                acc[i][j] = __builtin_amdgcn_mfma_f32_16x16x32_bf16(al[i], bh[j], acc[i][j], 0, 0, 0);
            }
    };
    auto loadAf = [&](int t, float4* f) {
        int r = tid >> 2, c = t * 32 + (tid & 3) * 8;
        if (bm + r < M) {
            const float* p = Af + (size_t)(bm + r) * K0 + c;
            f[0] = *(const float4*)p;
            f[1] = *(const float4*)(p + 4);
        } else {
            f[0] = f[1] = make_float4(0.f, 0.f, 0.f, 0.f);
        }
    };
    auto writeAf = [&](int buf, const float4* f) {
        int r = tid >> 2, kg = tid & 3;
        uint4 q0, q1;
        q0.x = pack_split(f[0].x); q0.y = pack_split(f[0].y);
        q0.z = pack_split(f[0].z); q0.w = pack_split(f[0].w);
        q1.x = pack_split(f[1].x); q1.y = pack_split(f[1].y);
        q1.z = pack_split(f[1].z); q1.w = pack_split(f[1].w);
        *(uint4*)(void*)As_p(buf, kg, 0, r) = q0;
        *(uint4*)(void*)As_p(buf, kg, 1, r) = q1;
    };

    zero_acc();

    // -------- stage 0: A from global --------
    {
        constexpr int NT = K0 / 32;
        float4 fA[2];
        if constexpr (AFP32) {
            loadAf(0, fA);
            stage_B(W0H, W0L, K0, 0, 0, 256);
            writeAf(0, fA);
        } else if constexpr (ATWO) {
            stage_A(Ap1, 0, 0);
            stage_B(W0H, W0L, 256, 0, 0, 256);
        } else {
            stage_A(Ap1, 0, 0);
            stage_B(W0H, W0L, K0, 0, 0, 256);
        }
        __syncthreads();
        for (int t = 0; t < NT; ++t) {
            int cur = t & 1;
            s8v ah[4], al[4], bh[4], bl[4];
            frags_A_As(cur, ah, al);
            frags_B(cur, bh, bl);
            if (t + 1 < NT) {
                if constexpr (AFP32) {
                    loadAf(t + 1, fA);
                    stage_B(W0H, W0L, K0, (t + 1) * 32, cur ^ 1, 256);
                } else if constexpr (ATWO) {
                    bool second = (t + 1) >= 8;
                    stage_A(second ? Ap2 : Ap1, ((t + 1) & 7) * 32, cur ^ 1);
                    stage_B(second ? W0H2 : W0H, second ? W0L2 : W0L,
                            256, ((t + 1) & 7) * 32, cur ^ 1, 256);
                } else {
                    stage_A(Ap1, (t + 1) * 32, cur ^ 1);
                    stage_B(W0H, W0L, K0, (t + 1) * 32, cur ^ 1, 256);
                }
            }
            do_mfma(ah, al, bh, bl);
            if constexpr (AFP32) { if (t + 1 < NT) writeAf(cur ^ 1, fA); }
            __syncthreads();
        }
    }

    // -------- stages 1..NST-1: A from LDS (x_lds) --------
    if constexpr (NST > 1) {
        // Xl: [8 kc][4 kg][2 half][64 row][4 u32] = 64 KB
        __shared__ __align__(16) unsigned Xl[8 * 4 * 2 * 64 * 4];
        auto Xl_p = [&](int kc, int kg, int half, int row) -> unsigned* {
            return Xl + (((kc * 4 + kg) * 2 + half) * 64 + row) * 4;
        };
        auto epi_X = [&](const float* bias) {
            #pragma unroll
            for (int j = 0; j < 4; ++j) {
                int col = w * 64 + j * 16 + li;
                float b = bias[col];
                #pragma unroll
                for (int i = 0; i < 4; ++i)
                    #pragma unroll
                    for (int r = 0; r < 4; ++r) {
                        int row = i * 16 + kq * 4 + r;
                        float v = fmaxf(acc[i][j][r] + b, 0.f);
                        *(Xl_p(col >> 5, (col & 31) >> 3, (col >> 2) & 1, row) + (col & 3)) = pack_split(v);
                    }
            }
        };
        auto frags_A_Xl = [&](int kc, s8v* ah, s8v* al) {
            #pragma unroll
            for (int i = 0; i < 4; ++i) {
                uint4 p0 = *(const uint4*)(const void*)Xl_p(kc, kq, 0, 16 * i + li);
                uint4 p1 = *(const uint4*)(const void*)Xl_p(kc, kq, 1, 16 * i + li);
                unpack8(p0, p1, ah[i], al[i]);
            }
        };

        // stage 1
        epi_X(bias0);
        __syncthreads();
        zero_acc();
        stage_B(W1H, W1L, 256, 0, 0, 256);
        __syncthreads();
        for (int t = 0; t < 8; ++t) {
            s8v ah[4], al[4], bh[4], bl[4];
            frags_A_Xl(t, ah, al);
            frags_B(t & 1, bh, bl);
            if (t < 7) stage_B(W1H, W1L, 256, (t + 1) * 32, (t & 1) ^ 1, 256);
            do_mfma(ah, al, bh, bl);
            __syncthreads();
        }
        // stage 2
        if constexpr (NST > 2) {
            epi_X(bias1);
            __syncthreads();
            zero_acc();
            stage_B(W2H, W2L, 256, 0, 0, NLAST);
            __syncthreads();
            for (int t = 0; t < 8; ++t) {
                s8v ah[4], al[4], bh[4], bl[4];
                frags_A_Xl(t, ah, al);
                frags_B(t & 1, bh, bl);
                if (t < 7) stage_B(W2H, W2L, 256, (t + 1) * 32, (t & 1) ^ 1, NLAST);
                do_mfma(ah, al, bh, bl);
                __syncthreads();
            }
        }
    }

    // -------- final epilogue --------
    const float* fb = (NST == 1) ? bias0 : ((NST == 2) ? bias1 : bias2);
    if constexpr (DOTANH) {
        #pragma unroll
        for (int j = 0; j < 4; ++j) {
            int col = w * 64 + j * 16 + li;
            if (col < NLAST) {
                float b = fb[col];
                #pragma unroll
                for (int i = 0; i < 4; ++i)
                    #pragma unroll
                    for (int r = 0; r < 4; ++r) {
                        int row = bm + i * 16 + kq * 4 + r;
                        if (row < M) Cf[(size_t)row * NLAST + col] = tanhf(acc[i][j][r] + b);
                    }
            }
        }
    } else {
        #pragma unroll
        for (int j = 0; j < 4; ++j) {
            int col = w * 64 + j * 16 + li;
            float b = fb[col];
            #pragma unroll
            for (int i = 0; i < 4; ++i)
                #pragma unroll
                for (int r = 0; r < 4; ++r) {
                    int row = bm + i * 16 + kq * 4 + r;
                    Cpk[(size_t)row * 256 + col] = pack_split(fmaxf(acc[i][j][r] + b, 0.f));
                }
        }
    }
}

// ---------------- launch ----------------

extern "C" void kernel_launch(void* const* d_in, const int* in_sizes, int n_in,
                              void* d_out, int out_size, void* d_ws, size_t ws_size,
                              hipStream_t stream) {
    const float* feat = (const float*)d_in[0];
    const int* einfo = (const int*)d_in[1];
    const float* b1 = (const float*)d_in[3];
    const float* b2 = (const float*)d_in[5];
    const float* b3 = (const float*)d_in[7];
    const float* bl1 = (const float*)d_in[9];
    const float* blH = (const float*)d_in[12];
    const float* bl2 = (const float*)d_in[15];
    const float* bp1 = (const float*)d_in[18];
    const float* bp2 = (const float*)d_in[20];
    const float* bp3 = (const float*)d_in[22];

    const int IN_DIM = 512;
    const int N = in_sizes[0] / IN_DIM;   // 50000
    const int E = in_sizes[1] / 2;        // 400000
    const int* src = einfo;
    const int* dst = einfo + E;
    const int M_pad = ((N + 63) / 64) * 64;         // 50048 (also mult of 64)
    const size_t PLANE_U = (size_t)M_pad * 256;     // packed u32 per activation

    unsigned* P0 = (unsigned*)d_ws;
    unsigned* P1 = P0 + PLANE_U;
    unsigned* P2 = P1 + PLANE_U;
    ushort* wsp = (ushort*)(P2 + PLANE_U);

    // weight table: {d_in idx, K, N}
    const int widx[12] = {2, 4, 6, 8, 10, 11, 13, 14, 16, 17, 19, 21};
    const int wK[12] = {512, 256, 256, 256, 256, 256, 256, 256, 256, 256, 256, 256};
    const int wN[12] = {256, 256, 256, 256, 256, 256, 256, 256, 256, 256, 256, 128};

    PrepArgs pa;
    ushort* Hp[12]; ushort* Lp[12];
    int acc_end = 0;
    ushort* cur = wsp;
    for (int i = 0; i < 12; ++i) {
        int elems = wK[i] * wN[i];
        pa.W[i] = (const float*)d_in[widx[i]];
        Hp[i] = cur; cur += elems;
        Lp[i] = cur; cur += elems;
        pa.H[i] = Hp[i];
        pa.L[i] = Lp[i];
        acc_end += elems;
        pa.end[i] = acc_end;
        pa.Kv[i] = wK[i];
        pa.nshift[i] = (wN[i] == 256) ? 8 : 7;
    }

    int* ioff = (int*)cur;
    int* icnt = ioff + (N + 1);
    int* icur = icnt + N;
    int* csr = icur + N;

    // CSR build + weight prep
    hipMemsetAsync(icnt, 0, (size_t)N * sizeof(int), stream);
    hipMemsetAsync(icur, 0, (size_t)N * sizeof(int), stream);
    hist_kernel<<<(E + 255) / 256, 256, 0, stream>>>(dst, icnt, E);
    scan_kernel<<<1, 1024, 0, stream>>>(icnt, ioff, N);
    scatter_kernel<<<(E + 255) / 256, 256, 0, stream>>>(src, dst, icur, ioff, csr, E);
    prep_weights<<<(acc_end + 255) / 256, 256, 0, stream>>>(pa, acc_end);

    const int GB = M_pad / 64;   // 782 blocks
    const int GA = (N + 3) / 4;  // aggregation blocks

    // F1: stem (feat fp32 -> 3 fused GEMMs) -> P0
    chain_kernel<3, 512, true, false, 256, false><<<GB, 256, 0, stream>>>(
        feat, nullptr, nullptr,
        Hp[0], Lp[0], nullptr, nullptr,
        Hp[1], Lp[1], Hp[2], Lp[2],
        b1, b2, b3, P0, nullptr, N);

    // SAGE 1
    sage_aggr_pk<<<GA, 256, 0, stream>>>(P0, csr, ioff, P1, N);
    chain_kernel<1, 512, false, true, 256, false><<<GB, 256, 0, stream>>>(
        nullptr, P1, P0,
        Hp[3], Lp[3], Hp[4], Lp[4],
        nullptr, nullptr, nullptr, nullptr,
        bl1, nullptr, nullptr, P2, nullptr, N);

    // SAGE 2
    sage_aggr_pk<<<GA, 256, 0, stream>>>(P2, csr, ioff, P1, N);
    chain_kernel<1, 512, false, true, 256, false><<<GB, 256, 0, stream>>>(
        nullptr, P1, P2,
        Hp[5], Lp[5], Hp[6], Lp[6],
        nullptr, nullptr, nullptr, nullptr,
        blH, nullptr, nullptr, P0, nullptr, N);

    // SAGE 3
    sage_aggr_pk<<<GA, 256, 0, stream>>>(P0, csr, ioff, P1, N);
    chain_kernel<1, 512, false, true, 256, false><<<GB, 256, 0, stream>>>(
        nullptr, P1, P0,
        Hp[7], Lp[7], Hp[8], Lp[8],
        nullptr, nullptr, nullptr, nullptr,
        bl2, nullptr, nullptr, P2, nullptr, N);

    // F2: head (3 fused GEMMs, last = 128 cols + tanh) -> d_out
    chain_kernel<3, 256, false, false, 128, true><<<GB, 256, 0, stream>>>(
        nullptr, P2, nullptr,
        Hp[9], Lp[9], nullptr, nullptr,
        Hp[10], Lp[10], Hp[11], Lp[11],
        bp1, bp2, bp3, nullptr, (float*)d_out, N);
}

// Round 6
// 839.902 us; speedup vs baseline: 1.5086x; 1.5086x over previous
//
#include <hip/hip_runtime.h>
#include <hip/hip_bf16.h>
#include <math.h>

typedef short s8v __attribute__((ext_vector_type(8)));
typedef float f32x4 __attribute__((ext_vector_type(4)));

__device__ __forceinline__ ushort f2bf(float f) {
    __hip_bfloat16 h = __float2bfloat16(f);
    return *reinterpret_cast<ushort*>(&h);
}
__device__ __forceinline__ float bf2f(ushort u) {
    return __uint_as_float(((unsigned)u) << 16);
}
__device__ __forceinline__ unsigned pack_split(float v) {
    ushort h = f2bf(v);
    ushort l = f2bf(v - bf2f(h));
    return ((unsigned)h << 16) | (unsigned)l;
}
__device__ __forceinline__ float unpack_f(unsigned p) {
    return __uint_as_float(p & 0xffff0000u) + __uint_as_float(p << 16);
}
__device__ __forceinline__ void gload16(const void* g, void* l) {
    __builtin_amdgcn_global_load_lds(
        (const __attribute__((address_space(1))) void*)g,
        (__attribute__((address_space(3))) void*)l, 16, 0, 0);
}
// 8 packed u32 (k0..7) -> hi frag / lo frag
__device__ __forceinline__ void unpack8(const uint4 p0, const uint4 p1, s8v& hi, s8v& lo) {
    union { s8v v; unsigned u[4]; } H, L;
    H.u[0] = (p0.x >> 16) | (p0.y & 0xffff0000u);
    H.u[1] = (p0.z >> 16) | (p0.w & 0xffff0000u);
    H.u[2] = (p1.x >> 16) | (p1.y & 0xffff0000u);
    H.u[3] = (p1.z >> 16) | (p1.w & 0xffff0000u);
    L.u[0] = (p0.x & 0xffffu) | (p0.y << 16);
    L.u[1] = (p0.z & 0xffffu) | (p0.w << 16);
    L.u[2] = (p1.x & 0xffffu) | (p1.y << 16);
    L.u[3] = (p1.z & 0xffffu) | (p1.w << 16);
    hi = H.v; lo = L.v;
}
// 8 fp32 -> hi/lo bf16 frags
__device__ __forceinline__ void cvt8(const uint4 p0, const uint4 p1, s8v& hi, s8v& lo) {
    union { s8v v; ushort e[8]; } H, L;
    float f[8] = {__uint_as_float(p0.x), __uint_as_float(p0.y),
                  __uint_as_float(p0.z), __uint_as_float(p0.w),
                  __uint_as_float(p1.x), __uint_as_float(p1.y),
                  __uint_as_float(p1.z), __uint_as_float(p1.w)};
    #pragma unroll
    for (int e = 0; e < 8; ++e) {
        ushort h = f2bf(f[e]);
        H.e[e] = (ushort)h;
        L.e[e] = f2bf(f[e] - bf2f(h));
    }
    hi = H.v; lo = L.v;
}

// ---------------- CSR build ----------------

__global__ __launch_bounds__(256)
void hist_kernel(const int* __restrict__ dst, int* __restrict__ cnt, int E) {
    int e = blockIdx.x * 256 + threadIdx.x;
    if (e < E) atomicAdd(&cnt[dst[e]], 1);
}

__global__ __launch_bounds__(1024)
void scan_kernel(const int* __restrict__ cnt, int* __restrict__ off, int n) {
    __shared__ int lds[1024];
    int t = threadIdx.x;
    int chunk = (n + 1023) >> 10;
    int begin = t * chunk;
    int end = min(begin + chunk, n);
    if (end < begin) end = begin;
    int s = 0;
    for (int i = begin; i < end; ++i) s += cnt[i];
    lds[t] = s;
    __syncthreads();
    for (int d = 1; d < 1024; d <<= 1) {
        int v = (t >= d) ? lds[t - d] : 0;
        __syncthreads();
        lds[t] += v;
        __syncthreads();
    }
    int pre = (t == 0) ? 0 : lds[t - 1];
    for (int i = begin; i < end; ++i) { off[i] = pre; pre += cnt[i]; }
    if (t == 1023) off[n] = pre;
}

__global__ __launch_bounds__(256)
void scatter_kernel(const int* __restrict__ src, const int* __restrict__ dst,
                    int* __restrict__ cur, const int* __restrict__ off,
                    int* __restrict__ csr, int E) {
    int e = blockIdx.x * 256 + threadIdx.x;
    if (e < E) {
        int d = dst[e];
        int pos = off[d] + atomicAdd(&cur[d], 1);
        csr[pos] = src[e];
    }
}

// ---------------- weight prep: transpose + pack (hi|lo u32), concat layout ----

struct PrepW {
    const float* W[12];
    unsigned* D[12];
    int end[12];
    int stride[12];   // dst row stride in u32 (K_total of the concat plane)
    int koff[12];     // dst k offset
    int nshift[12];   // log2(N_src)
};

__global__ __launch_bounds__(256)
void prep_weights(PrepW a, int total) {
    int id = blockIdx.x * 256 + threadIdx.x;
    if (id >= total) return;
    int s = 0;
    #pragma unroll
    for (int i = 0; i < 12; ++i) if (id >= a.end[i]) s = i + 1;
    int base = (s == 0) ? 0 : a.end[s - 1];
    int e = id - base;
    int Nmask = (1 << a.nshift[s]) - 1;
    int n = e & Nmask;
    int k = e >> a.nshift[s];
    float w = a.W[s][(size_t)k * (Nmask + 1) + n];
    a.D[s][(size_t)n * a.stride[s] + a.koff[s] + k] = pack_split(w);
}

// ---------------- per-dst online-softmax aggregation (packed u32) ----------------

__global__ __launch_bounds__(256)
void sage_aggr_pk(const unsigned* __restrict__ X, const int* __restrict__ csr,
                  const int* __restrict__ off, unsigned* __restrict__ O, int nN) {
    int node = blockIdx.x * 4 + (threadIdx.x >> 6);
    if (node >= nN) return;
    int c4 = (threadIdx.x & 63) * 4;
    int s0 = off[node], s1 = off[node + 1];
    float m0 = -INFINITY, m1 = -INFINITY, m2 = -INFINITY, m3 = -INFINITY;
    float se0 = 0, se1 = 0, se2 = 0, se3 = 0;
    float sm0 = 0, sm1 = 0, sm2 = 0, sm3 = 0;
#define ONLSTEP(vv, mm, ss, pp) { float nm = fmaxf(mm, vv); float r = __expf(mm - nm); \
    float p = __expf(vv - nm); ss = ss * r + p; pp = pp * r + p * (vv); mm = nm; }
    for (int j = s0; j < s1; ++j) {
        uint4 p = *(const uint4*)(X + (size_t)csr[j] * 256 + c4);
        float v0 = unpack_f(p.x), v1 = unpack_f(p.y), v2 = unpack_f(p.z), v3 = unpack_f(p.w);
        ONLSTEP(v0, m0, se0, sm0) ONLSTEP(v1, m1, se1, sm1)
        ONLSTEP(v2, m2, se2, sm2) ONLSTEP(v3, m3, se3, sm3)
    }
#undef ONLSTEP
    uint4 o;
    o.x = pack_split((s1 > s0) ? sm0 / se0 : 0.f);
    o.y = pack_split((s1 > s0) ? sm1 / se1 : 0.f);
    o.z = pack_split((s1 > s0) ? sm2 / se2 : 0.f);
    o.w = pack_split((s1 > s0) ? sm3 / se3 : 0.f);
    *(uint4*)(O + (size_t)node * 256 + c4) = o;
}

// ---------------- split-bf16 MFMA GEMM, counted-vmcnt 3-buffer pipeline ------
// C = act([A1|A2] @ B + bias).  BM=128, BN=256, BK=32, 512 threads (8 waves,
// each 64x64 = 4x4 16x16 frags).  3-term split: AhBh + AhBl + AlBh.
// LDS: 3 bufs x (A 128x32 + B 256x32) u32 = 144 KB.  One s_barrier per step;
// stage loads ride across 2 barriers; s_waitcnt vmcnt(6) (never 0 mid-loop).
// k-chunk (16B) XOR-swizzle: LDS[row][c] = global[row][c ^ (row&7)], applied
// on the STAGE SOURCE address (LDS dest stays linear for global_load_lds) and
// on the read side -> conflict-free ds_read_b128.

template<int NT1, int NT2, bool AF32, int NB, bool DOTANH>
__global__ __launch_bounds__(512, 2)
void gemm_pipe(const float* __restrict__ A1f, const unsigned* __restrict__ A1,
               const unsigned* __restrict__ A2,
               const unsigned* __restrict__ B,
               const float* __restrict__ bias,
               unsigned* __restrict__ Cpk, float* __restrict__ Cf, int M) {
    constexpr int NT = NT1 + NT2;
    constexpr int KU = NT * 32;           // total K (elements)
    __shared__ unsigned lds[3][12288];    // per buf: A [0,4096), B [4096,12288)

    const int tid = threadIdx.x;
    const int l = tid & 63;
    const int w = tid >> 6;               // 0..7
    const int wm = w >> 2, wn = w & 3;    // 2 x 4 wave grid
    const int li = l & 15, kq = l >> 4;
    const int bm = blockIdx.x * 128;

    const int srow = 8 * w + (l >> 3);          // staging row base (+64*s)
    const int schunk = (l & 7) ^ (l >> 3);      // swizzled source k-chunk

    f32x4 acc[4][4];
    #pragma unroll
    for (int i = 0; i < 4; ++i)
        #pragma unroll
        for (int j = 0; j < 4; ++j) acc[i][j] = (f32x4){0.f, 0.f, 0.f, 0.f};

    auto STAGE = [&](int t, int buf) {
        #pragma unroll
        for (int s = 0; s < 2; ++s) {           // A: 128 rows
            int r = 64 * s + srow;
            int gr = bm + r; gr = (gr < M) ? gr : (M - 1);
            const void* src;
            if constexpr (AF32) {
                src = A1f + (size_t)gr * KU + t * 32 + schunk * 4;
            } else if constexpr (NT2 > 0) {
                src = (t < NT1) ? (const void*)(A1 + (size_t)gr * (NT1 * 32) + t * 32 + schunk * 4)
                                : (const void*)(A2 + (size_t)gr * (NT2 * 32) + (t - NT1) * 32 + schunk * 4);
            } else {
                src = A1 + (size_t)gr * KU + t * 32 + schunk * 4;
            }
            gload16(src, &lds[buf][s * 2048 + w * 256 + l * 4]);
        }
        #pragma unroll
        for (int s = 0; s < 4; ++s) {           // B: 256 cols
            int n = 64 * s + srow;
            int gn = (n < NB) ? n : (NB - 1);
            const unsigned* src = B + (size_t)gn * KU + t * 32 + schunk * 4;
            gload16(src, &lds[buf][4096 + s * 2048 + w * 256 + l * 4]);
        }
    };

    auto COMPUTE = [&](int buf) {
        s8v bh[4], bl[4];
        #pragma unroll
        for (int j = 0; j < 4; ++j) {
            int col = wn * 64 + 16 * j + li;     // col & 7 == li & 7
            int base = 4096 + col * 32;
            uint4 p0 = *(const uint4*)&lds[buf][base + ((2 * kq)     ^ (li & 7)) * 4];
            uint4 p1 = *(const uint4*)&lds[buf][base + ((2 * kq + 1) ^ (li & 7)) * 4];
            unpack8(p0, p1, bh[j], bl[j]);
        }
        __builtin_amdgcn_s_setprio(1);
        #pragma unroll
        for (int i = 0; i < 4; ++i) {
            int row = wm * 64 + 16 * i + li;     // row & 7 == li & 7
            int base = row * 32;
            uint4 p0 = *(const uint4*)&lds[buf][base + ((2 * kq)     ^ (li & 7)) * 4];
            uint4 p1 = *(const uint4*)&lds[buf][base + ((2 * kq + 1) ^ (li & 7)) * 4];
            s8v ah, al;
            if constexpr (AF32) cvt8(p0, p1, ah, al);
            else                unpack8(p0, p1, ah, al);
            #pragma unroll
            for (int j = 0; j < 4; ++j) {
                acc[i][j] = __builtin_amdgcn_mfma_f32_16x16x32_bf16(ah, bh[j], acc[i][j], 0, 0, 0);
                acc[i][j] = __builtin_amdgcn_mfma_f32_16x16x32_bf16(ah, bl[j], acc[i][j], 0, 0, 0);
                acc[i][j] = __builtin_amdgcn_mfma_f32_16x16x32_bf16(al, bh[j], acc[i][j], 0, 0, 0);
            }
        }
        __builtin_amdgcn_s_setprio(0);
    };

    // prologue: 2 stages in flight (12 loads)
    STAGE(0, 0);
    STAGE(1, 1);
    #pragma unroll
    for (int t = 0; t < NT; ++t) {
        if (t + 1 < NT) asm volatile("s_waitcnt vmcnt(6)" ::: "memory");
        else            asm volatile("s_waitcnt vmcnt(0)" ::: "memory");
        __builtin_amdgcn_s_barrier();
        if (t + 2 < NT) STAGE(t + 2, (t + 2) % 3);
        COMPUTE(t % 3);
    }

    // epilogue.  C frag: col = lane&15, row = (lane>>4)*4 + reg
    #pragma unroll
    for (int j = 0; j < 4; ++j) {
        int col = wn * 64 + 16 * j + li;
        float b = bias[(col < NB) ? col : 0];
        #pragma unroll
        for (int i = 0; i < 4; ++i) {
            int row0 = bm + wm * 64 + 16 * i + kq * 4;
            #pragma unroll
            for (int r = 0; r < 4; ++r) {
                float v = acc[i][j][r] + b;
                if constexpr (DOTANH) {
                    if (row0 + r < M && col < NB)
                        Cf[(size_t)(row0 + r) * NB + col] = tanhf(v);
                } else {
                    Cpk[(size_t)(row0 + r) * 256 + col] = pack_split(fmaxf(v, 0.f));
                }
            }
        }
    }
}

// ---------------- launch ----------------

extern "C" void kernel_launch(void* const* d_in, const int* in_sizes, int n_in,
                              void* d_out, int out_size, void* d_ws, size_t ws_size,
                              hipStream_t stream) {
    const float* feat = (const float*)d_in[0];
    const int* einfo = (const int*)d_in[1];
    const float* b1 = (const float*)d_in[3];
    const float* b2 = (const float*)d_in[5];
    const float* b3 = (const float*)d_in[7];
    const float* bl1 = (const float*)d_in[9];
    const float* blH = (const float*)d_in[12];
    const float* bl2 = (const float*)d_in[15];
    const float* bp1 = (const float*)d_in[18];
    const float* bp2 = (const float*)d_in[20];
    const float* bp3 = (const float*)d_in[22];

    const int IN_DIM = 512;
    const int N = in_sizes[0] / IN_DIM;   // 50000
    const int E = in_sizes[1] / 2;        // 400000
    const int* src = einfo;
    const int* dst = einfo + E;
    const int M_pad = ((N + 127) / 128) * 128;      // 50176
    const size_t PLANE_U = (size_t)M_pad * 256;

    unsigned* P0 = (unsigned*)d_ws;
    unsigned* P1 = P0 + PLANE_U;
    unsigned* P2 = P1 + PLANE_U;
    unsigned* wp = P2 + PLANE_U;

    // packed weight planes (concat for fused SAGE GEMMs)
    // sizes in u32:
    const int gsz[9] = {131072, 65536, 65536, 131072, 131072, 131072, 65536, 65536, 32768};
    unsigned* G[9];
    {
        unsigned* c = wp;
        for (int i = 0; i < 9; ++i) { G[i] = c; c += gsz[i]; }
        wp = c;
    }

    // prep table: 12 source weights -> 9 planes
    // {d_in idx, dst plane, stride, koff, nshift}
    const int widx[12]   = {2, 4, 6, 8, 10, 11, 13, 14, 16, 17, 19, 21};
    const int wplane[12] = {0, 1, 2, 3, 3, 4, 4, 5, 5, 6, 7, 8};
    const int wstr[12]   = {512, 256, 256, 512, 512, 512, 512, 512, 512, 256, 256, 256};
    const int wkoff[12]  = {0, 0, 0, 0, 256, 0, 256, 0, 256, 0, 0, 0};
    const int wnsh[12]   = {8, 8, 8, 8, 8, 8, 8, 8, 8, 8, 8, 7};
    const int welem[12]  = {131072, 65536, 65536, 65536, 65536, 65536, 65536,
                            65536, 65536, 65536, 65536, 32768};

    PrepW pa;
    int acc_end = 0;
    for (int i = 0; i < 12; ++i) {
        pa.W[i] = (const float*)d_in[widx[i]];
        pa.D[i] = G[wplane[i]];
        pa.stride[i] = wstr[i];
        pa.koff[i] = wkoff[i];
        pa.nshift[i] = wnsh[i];
        acc_end += welem[i];
        pa.end[i] = acc_end;
    }

    int* ioff = (int*)wp;
    int* icnt = ioff + (N + 1);
    int* icur = icnt + N;
    int* csr = icur + N;

    // CSR build + weight prep
    hipMemsetAsync(icnt, 0, (size_t)N * sizeof(int), stream);
    hipMemsetAsync(icur, 0, (size_t)N * sizeof(int), stream);
    hist_kernel<<<(E + 255) / 256, 256, 0, stream>>>(dst, icnt, E);
    scan_kernel<<<1, 1024, 0, stream>>>(icnt, ioff, N);
    scatter_kernel<<<(E + 255) / 256, 256, 0, stream>>>(src, dst, icur, ioff, csr, E);
    prep_weights<<<(acc_end + 255) / 256, 256, 0, stream>>>(pa, acc_end);

    const int GB = M_pad / 128;   // 392 blocks
    const int GA = (N + 3) / 4;

    // stem
    gemm_pipe<16, 0, true, 256, false><<<GB, 512, 0, stream>>>(
        feat, nullptr, nullptr, G[0], b1, P0, nullptr, N);
    gemm_pipe<8, 0, false, 256, false><<<GB, 512, 0, stream>>>(
        nullptr, P0, nullptr, G[1], b2, P1, nullptr, N);
    gemm_pipe<8, 0, false, 256, false><<<GB, 512, 0, stream>>>(
        nullptr, P1, nullptr, G[2], b3, P0, nullptr, N);

    // SAGE 1: x = P0
    sage_aggr_pk<<<GA, 256, 0, stream>>>(P0, csr, ioff, P1, N);
    gemm_pipe<8, 8, false, 256, false><<<GB, 512, 0, stream>>>(
        nullptr, P1, P0, G[3], bl1, P2, nullptr, N);

    // SAGE 2: x = P2
    sage_aggr_pk<<<GA, 256, 0, stream>>>(P2, csr, ioff, P1, N);
    gemm_pipe<8, 8, false, 256, false><<<GB, 512, 0, stream>>>(
        nullptr, P1, P2, G[4], blH, P0, nullptr, N);

    // SAGE 3: x = P0
    sage_aggr_pk<<<GA, 256, 0, stream>>>(P0, csr, ioff, P1, N);
    gemm_pipe<8, 8, false, 256, false><<<GB, 512, 0, stream>>>(
        nullptr, P1, P0, G[5], bl2, P2, nullptr, N);

    // head
    gemm_pipe<8, 0, false, 256, false><<<GB, 512, 0, stream>>>(
        nullptr, P2, nullptr, G[6], bp1, P0, nullptr, N);
    gemm_pipe<8, 0, false, 256, false><<<GB, 512, 0, stream>>>(
        nullptr, P0, nullptr, G[7], bp2, P1, nullptr, N);
    gemm_pipe<8, 0, false, 128, true><<<GB, 512, 0, stream>>>(
        nullptr, P1, nullptr, G[8], bp3, nullptr, (float*)d_out, N);
}

// Round 7
// 742.607 us; speedup vs baseline: 1.7062x; 1.1310x over previous
//
#include <hip/hip_runtime.h>
#include <hip/hip_bf16.h>
#include <math.h>

typedef short s8v __attribute__((ext_vector_type(8)));
typedef float f32x4 __attribute__((ext_vector_type(4)));
typedef unsigned u32x4 __attribute__((ext_vector_type(4)));

__device__ __forceinline__ ushort f2bf(float f) {
    __hip_bfloat16 h = __float2bfloat16(f);
    return *reinterpret_cast<ushort*>(&h);
}
__device__ __forceinline__ float bf2f(ushort u) {
    return __uint_as_float(((unsigned)u) << 16);
}
__device__ __forceinline__ unsigned pack_split(float v) {
    ushort h = f2bf(v);
    ushort l = f2bf(v - bf2f(h));
    return ((unsigned)h << 16) | (unsigned)l;
}
__device__ __forceinline__ float unpack_f(unsigned p) {
    return __uint_as_float(p & 0xffff0000u) + __uint_as_float(p << 16);
}
__device__ __forceinline__ void gload16(const void* g, void* l) {
    __builtin_amdgcn_global_load_lds(
        (const __attribute__((address_space(1))) void*)g,
        (__attribute__((address_space(3))) void*)l, 16, 0, 0);
}
__device__ __forceinline__ unsigned lds_addr(const void* p) {
    return (unsigned)(size_t)(const __attribute__((address_space(3))) void*)p;
}
// 8 packed u32 (k0..7) -> hi frag / lo frag
__device__ __forceinline__ void unpack8(const u32x4 p0, const u32x4 p1, s8v& hi, s8v& lo) {
    union { s8v v; unsigned u[4]; } H, L;
    H.u[0] = (p0[0] >> 16) | (p0[1] & 0xffff0000u);
    H.u[1] = (p0[2] >> 16) | (p0[3] & 0xffff0000u);
    H.u[2] = (p1[0] >> 16) | (p1[1] & 0xffff0000u);
    H.u[3] = (p1[2] >> 16) | (p1[3] & 0xffff0000u);
    L.u[0] = (p0[0] & 0xffffu) | (p0[1] << 16);
    L.u[1] = (p0[2] & 0xffffu) | (p0[3] << 16);
    L.u[2] = (p1[0] & 0xffffu) | (p1[1] << 16);
    L.u[3] = (p1[2] & 0xffffu) | (p1[3] << 16);
    hi = H.v; lo = L.v;
}
// 8 fp32 -> hi/lo bf16 frags
__device__ __forceinline__ void cvt8(const u32x4 p0, const u32x4 p1, s8v& hi, s8v& lo) {
    union { s8v v; ushort e[8]; } H, L;
    float f[8] = {__uint_as_float(p0[0]), __uint_as_float(p0[1]),
                  __uint_as_float(p0[2]), __uint_as_float(p0[3]),
                  __uint_as_float(p1[0]), __uint_as_float(p1[1]),
                  __uint_as_float(p1[2]), __uint_as_float(p1[3])};
    #pragma unroll
    for (int e = 0; e < 8; ++e) {
        ushort h = f2bf(f[e]);
        H.e[e] = (ushort)h;
        L.e[e] = f2bf(f[e] - bf2f(h));
    }
    hi = H.v; lo = L.v;
}
template<bool AF32>
__device__ __forceinline__ void frag_a(const u32x4 p0, const u32x4 p1, s8v& hi, s8v& lo) {
    if constexpr (AF32) cvt8(p0, p1, hi, lo);
    else                unpack8(p0, p1, hi, lo);
}

#define DSR(dst, addr, OFF) \
    asm volatile("ds_read_b128 %0, %1 offset:" #OFF : "=v"(dst) : "v"(addr))

#define TRI(ah, al, bh, bl, C) \
    C = __builtin_amdgcn_mfma_f32_16x16x32_bf16(ah, bh, C, 0, 0, 0); \
    C = __builtin_amdgcn_mfma_f32_16x16x32_bf16(ah, bl, C, 0, 0, 0); \
    C = __builtin_amdgcn_mfma_f32_16x16x32_bf16(al, bh, C, 0, 0, 0);

// ---------------- CSR build ----------------

__global__ __launch_bounds__(256)
void hist_kernel(const int* __restrict__ dst, int* __restrict__ cnt, int E) {
    int e = blockIdx.x * 256 + threadIdx.x;
    if (e < E) atomicAdd(&cnt[dst[e]], 1);
}

__global__ __launch_bounds__(1024)
void scan_kernel(const int* __restrict__ cnt, int* __restrict__ off, int n) {
    __shared__ int lds[1024];
    int t = threadIdx.x;
    int chunk = (n + 1023) >> 10;
    int begin = t * chunk;
    int end = min(begin + chunk, n);
    if (end < begin) end = begin;
    int s = 0;
    for (int i = begin; i < end; ++i) s += cnt[i];
    lds[t] = s;
    __syncthreads();
    for (int d = 1; d < 1024; d <<= 1) {
        int v = (t >= d) ? lds[t - d] : 0;
        __syncthreads();
        lds[t] += v;
        __syncthreads();
    }
    int pre = (t == 0) ? 0 : lds[t - 1];
    for (int i = begin; i < end; ++i) { off[i] = pre; pre += cnt[i]; }
    if (t == 1023) off[n] = pre;
}

__global__ __launch_bounds__(256)
void scatter_kernel(const int* __restrict__ src, const int* __restrict__ dst,
                    int* __restrict__ cur, const int* __restrict__ off,
                    int* __restrict__ csr, int E) {
    int e = blockIdx.x * 256 + threadIdx.x;
    if (e < E) {
        int d = dst[e];
        int pos = off[d] + atomicAdd(&cur[d], 1);
        csr[pos] = src[e];
    }
}

// ---------------- weight prep: transpose + pack (hi|lo u32), concat layout ----

struct PrepW {
    const float* W[12];
    unsigned* D[12];
    int end[12];
    int stride[12];
    int koff[12];
    int nshift[12];
};

__global__ __launch_bounds__(256)
void prep_weights(PrepW a, int total) {
    int id = blockIdx.x * 256 + threadIdx.x;
    if (id >= total) return;
    int s = 0;
    #pragma unroll
    for (int i = 0; i < 12; ++i) if (id >= a.end[i]) s = i + 1;
    int base = (s == 0) ? 0 : a.end[s - 1];
    int e = id - base;
    int Nmask = (1 << a.nshift[s]) - 1;
    int n = e & Nmask;
    int k = e >> a.nshift[s];
    float w = a.W[s][(size_t)k * (Nmask + 1) + n];
    a.D[s][(size_t)n * a.stride[s] + a.koff[s] + k] = pack_split(w);
}

// ---------------- per-dst online-softmax aggregation (packed u32) ----------------

__global__ __launch_bounds__(256)
void sage_aggr_pk(const unsigned* __restrict__ X, const int* __restrict__ csr,
                  const int* __restrict__ off, unsigned* __restrict__ O, int nN) {
    int node = blockIdx.x * 4 + (threadIdx.x >> 6);
    if (node >= nN) return;
    int c4 = (threadIdx.x & 63) * 4;
    int s0 = off[node], s1 = off[node + 1];
    float m0 = -INFINITY, m1 = -INFINITY, m2 = -INFINITY, m3 = -INFINITY;
    float se0 = 0, se1 = 0, se2 = 0, se3 = 0;
    float sm0 = 0, sm1 = 0, sm2 = 0, sm3 = 0;
#define ONLSTEP(vv, mm, ss, pp) { float nm = fmaxf(mm, vv); float r = __expf(mm - nm); \
    float p = __expf(vv - nm); ss = ss * r + p; pp = pp * r + p * (vv); mm = nm; }
    for (int j = s0; j < s1; ++j) {
        uint4 p = *(const uint4*)(X + (size_t)csr[j] * 256 + c4);
        float v0 = unpack_f(p.x), v1 = unpack_f(p.y), v2 = unpack_f(p.z), v3 = unpack_f(p.w);
        ONLSTEP(v0, m0, se0, sm0) ONLSTEP(v1, m1, se1, sm1)
        ONLSTEP(v2, m2, se2, sm2) ONLSTEP(v3, m3, se3, sm3)
    }
#undef ONLSTEP
    uint4 o;
    o.x = pack_split((s1 > s0) ? sm0 / se0 : 0.f);
    o.y = pack_split((s1 > s0) ? sm1 / se1 : 0.f);
    o.z = pack_split((s1 > s0) ? sm2 / se2 : 0.f);
    o.w = pack_split((s1 > s0) ? sm3 / se3 : 0.f);
    *(uint4*)(O + (size_t)node * 256 + c4) = o;
}

// ---------------- split-bf16 MFMA GEMM, counted-vmcnt + asm ds_read pipeline --
// Same geometry as round 6 (BM=128, BN=256, BK=32, 8 waves, 3 LDS bufs,
// vmcnt(6), one s_barrier/step, XOR-swizzled k-chunks). Delta: ALL fragment
// reads are inline-asm ds_read_b128 with manual lgkmcnt(0)+sched_barrier(0)
// (rule #18) so the compiler cannot tie them to global_load_lds and insert
// conservative vmcnt drains.

template<int NT1, int NT2, bool AF32, int NB, bool DOTANH>
__global__ __launch_bounds__(512, 2)
void gemm_pipe(const float* __restrict__ A1f, const unsigned* __restrict__ A1,
               const unsigned* __restrict__ A2,
               const unsigned* __restrict__ B,
               const float* __restrict__ bias,
               unsigned* __restrict__ Cpk, float* __restrict__ Cf, int M) {
    constexpr int NT = NT1 + NT2;
    constexpr int KU = NT * 32;
    __shared__ unsigned lds[3][12288];    // per buf: A [0,4096), B [4096,12288)

    const int tid = threadIdx.x;
    const int l = tid & 63;
    const int w = tid >> 6;
    const int wm = w >> 2, wn = w & 3;
    const int li = l & 15, kq = l >> 4;
    const int bm = blockIdx.x * 128;

    const int srow = 8 * w + (l >> 3);
    const int schunk = (l & 7) ^ (l >> 3);

    const unsigned lbase = lds_addr(&lds[0][0]);
    const unsigned swz0 = (unsigned)((((2 * kq)) ^ (li & 7)) * 16);
    const unsigned aoff = (unsigned)((wm * 64 + li) * 128) + swz0;
    const unsigned boff = 16384u + (unsigned)((wn * 64 + li) * 128) + swz0;

    f32x4 acc[4][4];
    #pragma unroll
    for (int i = 0; i < 4; ++i)
        #pragma unroll
        for (int j = 0; j < 4; ++j) acc[i][j] = (f32x4){0.f, 0.f, 0.f, 0.f};

    auto STAGE = [&](int t, int buf) {
        #pragma unroll
        for (int s = 0; s < 2; ++s) {           // A: 128 rows
            int r = 64 * s + srow;
            int gr = bm + r; gr = (gr < M) ? gr : (M - 1);
            const void* src;
            if constexpr (AF32) {
                src = A1f + (size_t)gr * KU + t * 32 + schunk * 4;
            } else if constexpr (NT2 > 0) {
                src = (t < NT1) ? (const void*)(A1 + (size_t)gr * (NT1 * 32) + t * 32 + schunk * 4)
                                : (const void*)(A2 + (size_t)gr * (NT2 * 32) + (t - NT1) * 32 + schunk * 4);
            } else {
                src = A1 + (size_t)gr * KU + t * 32 + schunk * 4;
            }
            gload16(src, &lds[buf][s * 2048 + w * 256 + l * 4]);
        }
        #pragma unroll
        for (int s = 0; s < 4; ++s) {           // B: 256 cols
            int n = 64 * s + srow;
            int gn = (n < NB) ? n : (NB - 1);
            const unsigned* src = B + (size_t)gn * KU + t * 32 + schunk * 4;
            gload16(src, &lds[buf][4096 + s * 2048 + w * 256 + l * 4]);
        }
    };

    // prologue: 2 stages in flight (12 loads)
    STAGE(0, 0);
    STAGE(1, 1);

    #pragma unroll
    for (int t = 0; t < NT; ++t) {
        if (t + 1 < NT) asm volatile("s_waitcnt vmcnt(6)" ::: "memory");
        else            asm volatile("s_waitcnt vmcnt(0)" ::: "memory");
        __builtin_amdgcn_s_barrier();

        const int buf = t % 3;
        const unsigned lb = lbase + (unsigned)buf * 49152u;
        unsigned ab = lb + aoff, bb = lb + boff;
        unsigned ab1 = ab ^ 16u, bb1 = bb ^ 16u;

        u32x4 B0, B1, B2, B3, B4, B5, B6, B7;
        u32x4 A0, A1v, A2v, A3, A4, A5, A6, A7;
        DSR(B0, bb, 0);    DSR(B1, bb, 2048);  DSR(B2, bb, 4096);  DSR(B3, bb, 6144);
        DSR(B4, bb1, 0);   DSR(B5, bb1, 2048); DSR(B6, bb1, 4096); DSR(B7, bb1, 6144);
        DSR(A0, ab, 0);    DSR(A1v, ab, 2048); DSR(A2v, ab, 4096); DSR(A3, ab, 6144);
        DSR(A4, ab1, 0);   DSR(A5, ab1, 2048); DSR(A6, ab1, 4096); DSR(A7, ab1, 6144);
        __builtin_amdgcn_sched_barrier(0);

        if (t + 2 < NT) STAGE(t + 2, (t + 2) % 3);
        __builtin_amdgcn_sched_barrier(0);

        asm volatile("s_waitcnt lgkmcnt(0)" ::: "memory");
        __builtin_amdgcn_sched_barrier(0);

        s8v bh0, bl0, bh1, bl1, bh2, bl2, bh3, bl3;
        unpack8(B0, B4, bh0, bl0);
        unpack8(B1, B5, bh1, bl1);
        unpack8(B2, B6, bh2, bl2);
        unpack8(B3, B7, bh3, bl3);

        __builtin_amdgcn_s_setprio(1);
        {
            s8v ah, al;
            frag_a<AF32>(A0, A4, ah, al);
            TRI(ah, al, bh0, bl0, acc[0][0]) TRI(ah, al, bh1, bl1, acc[0][1])
            TRI(ah, al, bh2, bl2, acc[0][2]) TRI(ah, al, bh3, bl3, acc[0][3])
        }
        {
            s8v ah, al;
            frag_a<AF32>(A1v, A5, ah, al);
            TRI(ah, al, bh0, bl0, acc[1][0]) TRI(ah, al, bh1, bl1, acc[1][1])
            TRI(ah, al, bh2, bl2, acc[1][2]) TRI(ah, al, bh3, bl3, acc[1][3])
        }
        {
            s8v ah, al;
            frag_a<AF32>(A2v, A6, ah, al);
            TRI(ah, al, bh0, bl0, acc[2][0]) TRI(ah, al, bh1, bl1, acc[2][1])
            TRI(ah, al, bh2, bl2, acc[2][2]) TRI(ah, al, bh3, bl3, acc[2][3])
        }
        {
            s8v ah, al;
            frag_a<AF32>(A3, A7, ah, al);
            TRI(ah, al, bh0, bl0, acc[3][0]) TRI(ah, al, bh1, bl1, acc[3][1])
            TRI(ah, al, bh2, bl2, acc[3][2]) TRI(ah, al, bh3, bl3, acc[3][3])
        }
        __builtin_amdgcn_s_setprio(0);
    }

    // epilogue.  C frag: col = lane&15, row = (lane>>4)*4 + reg
    #pragma unroll
    for (int j = 0; j < 4; ++j) {
        int col = wn * 64 + 16 * j + li;
        float b = bias[(col < NB) ? col : 0];
        #pragma unroll
        for (int i = 0; i < 4; ++i) {
            int row0 = bm + wm * 64 + 16 * i + kq * 4;
            #pragma unroll
            for (int r = 0; r < 4; ++r) {
                float v = acc[i][j][r] + b;
                if constexpr (DOTANH) {
                    if (row0 + r < M && col < NB)
                        Cf[(size_t)(row0 + r) * NB + col] = tanhf(v);
                } else {
                    Cpk[(size_t)(row0 + r) * 256 + col] = pack_split(fmaxf(v, 0.f));
                }
            }
        }
    }
}

// ---------------- launch ----------------

extern "C" void kernel_launch(void* const* d_in, const int* in_sizes, int n_in,
                              void* d_out, int out_size, void* d_ws, size_t ws_size,
                              hipStream_t stream) {
    const float* feat = (const float*)d_in[0];
    const int* einfo = (const int*)d_in[1];
    const float* b1 = (const float*)d_in[3];
    const float* b2 = (const float*)d_in[5];
    const float* b3 = (const float*)d_in[7];
    const float* bl1 = (const float*)d_in[9];
    const float* blH = (const float*)d_in[12];
    const float* bl2 = (const float*)d_in[15];
    const float* bp1 = (const float*)d_in[18];
    const float* bp2 = (const float*)d_in[20];
    const float* bp3 = (const float*)d_in[22];

    const int IN_DIM = 512;
    const int N = in_sizes[0] / IN_DIM;   // 50000
    const int E = in_sizes[1] / 2;        // 400000
    const int* src = einfo;
    const int* dst = einfo + E;
    const int M_pad = ((N + 127) / 128) * 128;      // 50176
    const size_t PLANE_U = (size_t)M_pad * 256;

    unsigned* P0 = (unsigned*)d_ws;
    unsigned* P1 = P0 + PLANE_U;
    unsigned* P2 = P1 + PLANE_U;
    unsigned* wp = P2 + PLANE_U;

    // packed weight planes (concat for fused SAGE GEMMs), sizes in u32
    const int gsz[9] = {131072, 65536, 65536, 131072, 131072, 131072, 65536, 65536, 32768};
    unsigned* G[9];
    {
        unsigned* c = wp;
        for (int i = 0; i < 9; ++i) { G[i] = c; c += gsz[i]; }
        wp = c;
    }

    const int widx[12]   = {2, 4, 6, 8, 10, 11, 13, 14, 16, 17, 19, 21};
    const int wplane[12] = {0, 1, 2, 3, 3, 4, 4, 5, 5, 6, 7, 8};
    const int wstr[12]   = {512, 256, 256, 512, 512, 512, 512, 512, 512, 256, 256, 256};
    const int wkoff[12]  = {0, 0, 0, 0, 256, 0, 256, 0, 256, 0, 0, 0};
    const int wnsh[12]   = {8, 8, 8, 8, 8, 8, 8, 8, 8, 8, 8, 7};
    const int welem[12]  = {131072, 65536, 65536, 65536, 65536, 65536, 65536,
                            65536, 65536, 65536, 65536, 32768};

    PrepW pa;
    int acc_end = 0;
    for (int i = 0; i < 12; ++i) {
        pa.W[i] = (const float*)d_in[widx[i]];
        pa.D[i] = G[wplane[i]];
        pa.stride[i] = wstr[i];
        pa.koff[i] = wkoff[i];
        pa.nshift[i] = wnsh[i];
        acc_end += welem[i];
        pa.end[i] = acc_end;
    }

    int* ioff = (int*)wp;
    int* icnt = ioff + (N + 1);
    int* icur = icnt + N;
    int* csr = icur + N;

    // CSR build + weight prep
    hipMemsetAsync(icnt, 0, (size_t)N * sizeof(int), stream);
    hipMemsetAsync(icur, 0, (size_t)N * sizeof(int), stream);
    hist_kernel<<<(E + 255) / 256, 256, 0, stream>>>(dst, icnt, E);
    scan_kernel<<<1, 1024, 0, stream>>>(icnt, ioff, N);
    scatter_kernel<<<(E + 255) / 256, 256, 0, stream>>>(src, dst, icur, ioff, csr, E);
    prep_weights<<<(acc_end + 255) / 256, 256, 0, stream>>>(pa, acc_end);

    const int GB = M_pad / 128;   // 392 blocks
    const int GA = (N + 3) / 4;

    // stem
    gemm_pipe<16, 0, true, 256, false><<<GB, 512, 0, stream>>>(
        feat, nullptr, nullptr, G[0], b1, P0, nullptr, N);
    gemm_pipe<8, 0, false, 256, false><<<GB, 512, 0, stream>>>(
        nullptr, P0, nullptr, G[1], b2, P1, nullptr, N);
    gemm_pipe<8, 0, false, 256, false><<<GB, 512, 0, stream>>>(
        nullptr, P1, nullptr, G[2], b3, P0, nullptr, N);

    // SAGE 1: x = P0
    sage_aggr_pk<<<GA, 256, 0, stream>>>(P0, csr, ioff, P1, N);
    gemm_pipe<8, 8, false, 256, false><<<GB, 512, 0, stream>>>(
        nullptr, P1, P0, G[3], bl1, P2, nullptr, N);

    // SAGE 2: x = P2
    sage_aggr_pk<<<GA, 256, 0, stream>>>(P2, csr, ioff, P1, N);
    gemm_pipe<8, 8, false, 256, false><<<GB, 512, 0, stream>>>(
        nullptr, P1, P2, G[4], blH, P0, nullptr, N);

    // SAGE 3: x = P0
    sage_aggr_pk<<<GA, 256, 0, stream>>>(P0, csr, ioff, P1, N);
    gemm_pipe<8, 8, false, 256, false><<<GB, 512, 0, stream>>>(
        nullptr, P1, P0, G[5], bl2, P2, nullptr, N);

    // head
    gemm_pipe<8, 0, false, 256, false><<<GB, 512, 0, stream>>>(
        nullptr, P2, nullptr, G[6], bp1, P0, nullptr, N);
    gemm_pipe<8, 0, false, 256, false><<<GB, 512, 0, stream>>>(
        nullptr, P0, nullptr, G[7], bp2, P1, nullptr, N);
    gemm_pipe<8, 0, false, 128, true><<<GB, 512, 0, stream>>>(
        nullptr, P1, nullptr, G[8], bp3, nullptr, (float*)d_out, N);
}

// Round 8
// 652.139 us; speedup vs baseline: 1.9429x; 1.1387x over previous
//
#include <hip/hip_runtime.h>
#include <hip/hip_bf16.h>
#include <math.h>

typedef short s8v __attribute__((ext_vector_type(8)));
typedef float f32x4 __attribute__((ext_vector_type(4)));
typedef unsigned u32x4 __attribute__((ext_vector_type(4)));

__device__ __forceinline__ ushort f2bf(float f) {
    __hip_bfloat16 h = __float2bfloat16(f);
    return *reinterpret_cast<ushort*>(&h);
}
__device__ __forceinline__ float bf2f(ushort u) {
    return __uint_as_float(((unsigned)u) << 16);
}
__device__ __forceinline__ unsigned pack_split(float v) {
    ushort h = f2bf(v);
    ushort l = f2bf(v - bf2f(h));
    return ((unsigned)h << 16) | (unsigned)l;
}
__device__ __forceinline__ float unpack_f(unsigned p) {
    return __uint_as_float(p & 0xffff0000u) + __uint_as_float(p << 16);
}
__device__ __forceinline__ void gload16(const void* g, void* l) {
    __builtin_amdgcn_global_load_lds(
        (const __attribute__((address_space(1))) void*)g,
        (__attribute__((address_space(3))) void*)l, 16, 0, 0);
}
__device__ __forceinline__ unsigned lds_addr(const void* p) {
    return (unsigned)(size_t)(const __attribute__((address_space(3))) void*)p;
}
// 8 packed u32 (k0..7) -> hi frag / lo frag
__device__ __forceinline__ void unpack8(const u32x4 p0, const u32x4 p1, s8v& hi, s8v& lo) {
    union { s8v v; unsigned u[4]; } H, L;
    H.u[0] = (p0[0] >> 16) | (p0[1] & 0xffff0000u);
    H.u[1] = (p0[2] >> 16) | (p0[3] & 0xffff0000u);
    H.u[2] = (p1[0] >> 16) | (p1[1] & 0xffff0000u);
    H.u[3] = (p1[2] >> 16) | (p1[3] & 0xffff0000u);
    L.u[0] = (p0[0] & 0xffffu) | (p0[1] << 16);
    L.u[1] = (p0[2] & 0xffffu) | (p0[3] << 16);
    L.u[2] = (p1[0] & 0xffffu) | (p1[1] << 16);
    L.u[3] = (p1[2] & 0xffffu) | (p1[3] << 16);
    hi = H.v; lo = L.v;
}
// 8 fp32 -> hi/lo bf16 frags
__device__ __forceinline__ void cvt8(const u32x4 p0, const u32x4 p1, s8v& hi, s8v& lo) {
    union { s8v v; ushort e[8]; } H, L;
    float f[8] = {__uint_as_float(p0[0]), __uint_as_float(p0[1]),
                  __uint_as_float(p0[2]), __uint_as_float(p0[3]),
                  __uint_as_float(p1[0]), __uint_as_float(p1[1]),
                  __uint_as_float(p1[2]), __uint_as_float(p1[3])};
    #pragma unroll
    for (int e = 0; e < 8; ++e) {
        ushort h = f2bf(f[e]);
        H.e[e] = (ushort)h;
        L.e[e] = f2bf(f[e] - bf2f(h));
    }
    hi = H.v; lo = L.v;
}
template<bool AF32>
__device__ __forceinline__ void frag_a(const u32x4 p0, const u32x4 p1, s8v& hi, s8v& lo) {
    if constexpr (AF32) cvt8(p0, p1, hi, lo);
    else                unpack8(p0, p1, hi, lo);
}

#define DSR(dst, addr, OFF) \
    asm volatile("ds_read_b128 %0, %1 offset:" #OFF : "=v"(dst) : "v"(addr))

#define TRI(ah, al, bh, bl, C) \
    C = __builtin_amdgcn_mfma_f32_16x16x32_bf16(ah, bh, C, 0, 0, 0); \
    C = __builtin_amdgcn_mfma_f32_16x16x32_bf16(ah, bl, C, 0, 0, 0); \
    C = __builtin_amdgcn_mfma_f32_16x16x32_bf16(al, bh, C, 0, 0, 0);

// ---------------- CSR build ----------------

__global__ __launch_bounds__(256)
void hist_kernel(const int* __restrict__ dst, int* __restrict__ cnt, int E) {
    int e = blockIdx.x * 256 + threadIdx.x;
    if (e < E) atomicAdd(&cnt[dst[e]], 1);
}

// parallel scan, 3 kernels: per-1024-chunk sums -> 1-wave scan -> local offsets
__global__ __launch_bounds__(256)
void scan_part(const int* __restrict__ cnt, int* __restrict__ bsum, int n) {
    __shared__ int s[256];
    int b = blockIdx.x, t = threadIdx.x;
    int i0 = b * 1024 + t * 4;
    int v = 0;
    if (i0 + 3 < n) {
        int4 q = *(const int4*)(cnt + i0);
        v = q.x + q.y + q.z + q.w;
    } else {
        for (int i = 0; i < 4; ++i) if (i0 + i < n) v += cnt[i0 + i];
    }
    s[t] = v;
    __syncthreads();
    for (int d = 128; d > 0; d >>= 1) {
        if (t < d) s[t] += s[t + d];
        __syncthreads();
    }
    if (t == 0) bsum[b] = s[0];
}

__global__ __launch_bounds__(64)
void scan_top(int* __restrict__ bsum, int nb) {
    int l = threadIdx.x;
    int own = (l < nb) ? bsum[l] : 0;
    int v = own;
    #pragma unroll
    for (int d = 1; d < 64; d <<= 1) {
        int u = __shfl_up(v, d, 64);
        if (l >= d) v += u;
    }
    if (l < nb) bsum[l] = v - own;   // exclusive
}

__global__ __launch_bounds__(256)
void scan_final(const int* __restrict__ cnt, const int* __restrict__ bsum,
                int* __restrict__ off, int n, int E) {
    __shared__ int s[256];
    int b = blockIdx.x, t = threadIdx.x;
    int i0 = b * 1024 + t * 4;
    int v0 = 0, v1 = 0, v2 = 0, v3 = 0;
    if (i0 + 3 < n) {
        int4 q = *(const int4*)(cnt + i0);
        v0 = q.x; v1 = q.y; v2 = q.z; v3 = q.w;
    } else {
        if (i0     < n) v0 = cnt[i0];
        if (i0 + 1 < n) v1 = cnt[i0 + 1];
        if (i0 + 2 < n) v2 = cnt[i0 + 2];
        if (i0 + 3 < n) v3 = cnt[i0 + 3];
    }
    int tsum = v0 + v1 + v2 + v3;
    s[t] = tsum;
    __syncthreads();
    for (int d = 1; d < 256; d <<= 1) {
        int u = (t >= d) ? s[t - d] : 0;
        __syncthreads();
        s[t] += u;
        __syncthreads();
    }
    int excl = s[t] - tsum + bsum[b];
    if (i0     < n) off[i0]     = excl;
    if (i0 + 1 < n) off[i0 + 1] = excl + v0;
    if (i0 + 2 < n) off[i0 + 2] = excl + v0 + v1;
    if (i0 + 3 < n) off[i0 + 3] = excl + v0 + v1 + v2;
    if (b == 0 && t == 0) off[n] = E;
}

__global__ __launch_bounds__(256)
void scatter_kernel(const int* __restrict__ src, const int* __restrict__ dst,
                    int* __restrict__ cur, const int* __restrict__ off,
                    int* __restrict__ csr, int E) {
    int e = blockIdx.x * 256 + threadIdx.x;
    if (e < E) {
        int d = dst[e];
        int pos = off[d] + atomicAdd(&cur[d], 1);
        csr[pos] = src[e];
    }
}

// ---------------- weight prep: transpose + pack (hi|lo u32), concat layout ----

struct PrepW {
    const float* W[12];
    unsigned* D[12];
    int end[12];
    int stride[12];
    int koff[12];
    int nshift[12];
};

__global__ __launch_bounds__(256)
void prep_weights(PrepW a, int total) {
    int id = blockIdx.x * 256 + threadIdx.x;
    if (id >= total) return;
    int s = 0;
    #pragma unroll
    for (int i = 0; i < 12; ++i) if (id >= a.end[i]) s = i + 1;
    int base = (s == 0) ? 0 : a.end[s - 1];
    int e = id - base;
    int Nmask = (1 << a.nshift[s]) - 1;
    int n = e & Nmask;
    int k = e >> a.nshift[s];
    float w = a.W[s][(size_t)k * (Nmask + 1) + n];
    a.D[s][(size_t)n * a.stride[s] + a.koff[s] + k] = pack_split(w);
}

// ---------------- per-dst online-softmax aggregation (packed u32) ----------------

__global__ __launch_bounds__(256)
void sage_aggr_pk(const unsigned* __restrict__ X, const int* __restrict__ csr,
                  const int* __restrict__ off, unsigned* __restrict__ O, int nN) {
    int node = blockIdx.x * 4 + (threadIdx.x >> 6);
    if (node >= nN) return;
    int c4 = (threadIdx.x & 63) * 4;
    int s0 = off[node], s1 = off[node + 1];
    float m0 = -INFINITY, m1 = -INFINITY, m2 = -INFINITY, m3 = -INFINITY;
    float se0 = 0, se1 = 0, se2 = 0, se3 = 0;
    float sm0 = 0, sm1 = 0, sm2 = 0, sm3 = 0;
#define ONLSTEP(vv, mm, ss, pp) { float nm = fmaxf(mm, vv); float r = __expf(mm - nm); \
    float p = __expf(vv - nm); ss = ss * r + p; pp = pp * r + p * (vv); mm = nm; }
    for (int j = s0; j < s1; ++j) {
        uint4 p = *(const uint4*)(X + (size_t)csr[j] * 256 + c4);
        float v0 = unpack_f(p.x), v1 = unpack_f(p.y), v2 = unpack_f(p.z), v3 = unpack_f(p.w);
        ONLSTEP(v0, m0, se0, sm0) ONLSTEP(v1, m1, se1, sm1)
        ONLSTEP(v2, m2, se2, sm2) ONLSTEP(v3, m3, se3, sm3)
    }
#undef ONLSTEP
    uint4 o;
    o.x = pack_split((s1 > s0) ? sm0 / se0 : 0.f);
    o.y = pack_split((s1 > s0) ? sm1 / se1 : 0.f);
    o.z = pack_split((s1 > s0) ? sm2 / se2 : 0.f);
    o.w = pack_split((s1 > s0) ? sm3 / se3 : 0.f);
    *(uint4*)(O + (size_t)node * 256 + c4) = o;
}

// ---------------- split-bf16 MFMA GEMM, counted vmcnt+lgkmcnt pipeline --------
// Geometry as round 6/7 (BM=128, BN=256, BK=32, 8 waves, 3 LDS bufs, vmcnt(6),
// one s_barrier/step, XOR-swizzled k-chunks, asm ds_read). Delta vs round 7:
// A-row fragment reads are issued BETWEEN MFMA clusters with counted
// lgkmcnt(2) waits, so LDS latency hides under MFMA instead of serializing.

template<int NT1, int NT2, bool AF32, int NB, bool DOTANH>
__global__ __launch_bounds__(512, 2)
void gemm_pipe(const float* __restrict__ A1f, const unsigned* __restrict__ A1,
               const unsigned* __restrict__ A2,
               const unsigned* __restrict__ B,
               const float* __restrict__ bias,
               unsigned* __restrict__ Cpk, float* __restrict__ Cf, int M) {
    constexpr int NT = NT1 + NT2;
    constexpr int KU = NT * 32;
    __shared__ unsigned lds[3][12288];    // per buf: A [0,4096), B [4096,12288)

    const int tid = threadIdx.x;
    const int l = tid & 63;
    const int w = tid >> 6;
    const int wm = w >> 2, wn = w & 3;
    const int li = l & 15, kq = l >> 4;
    const int bm = blockIdx.x * 128;

    const int srow = 8 * w + (l >> 3);
    const int schunk = (l & 7) ^ (l >> 3);

    const unsigned lbase = lds_addr(&lds[0][0]);
    const unsigned swz0 = (unsigned)((((2 * kq)) ^ (li & 7)) * 16);
    const unsigned aoff = (unsigned)((wm * 64 + li) * 128) + swz0;
    const unsigned boff = 16384u + (unsigned)((wn * 64 + li) * 128) + swz0;

    f32x4 acc[4][4];
    #pragma unroll
    for (int i = 0; i < 4; ++i)
        #pragma unroll
        for (int j = 0; j < 4; ++j) acc[i][j] = (f32x4){0.f, 0.f, 0.f, 0.f};

    auto STAGE = [&](int t, int buf) {
        #pragma unroll
        for (int s = 0; s < 2; ++s) {           // A: 128 rows
            int r = 64 * s + srow;
            int gr = bm + r; gr = (gr < M) ? gr : (M - 1);
            const void* src;
            if constexpr (AF32) {
                src = A1f + (size_t)gr * KU + t * 32 + schunk * 4;
            } else if constexpr (NT2 > 0) {
                src = (t < NT1) ? (const void*)(A1 + (size_t)gr * (NT1 * 32) + t * 32 + schunk * 4)
                                : (const void*)(A2 + (size_t)gr * (NT2 * 32) + (t - NT1) * 32 + schunk * 4);
            } else {
                src = A1 + (size_t)gr * KU + t * 32 + schunk * 4;
            }
            gload16(src, &lds[buf][s * 2048 + w * 256 + l * 4]);
        }
        #pragma unroll
        for (int s = 0; s < 4; ++s) {           // B: 256 cols
            int n = 64 * s + srow;
            int gn = (n < NB) ? n : (NB - 1);
            const unsigned* src = B + (size_t)gn * KU + t * 32 + schunk * 4;
            gload16(src, &lds[buf][4096 + s * 2048 + w * 256 + l * 4]);
        }
    };

    // prologue: 2 stages in flight (12 loads)
    STAGE(0, 0);
    STAGE(1, 1);

    #pragma unroll
    for (int t = 0; t < NT; ++t) {
        if (t + 1 < NT) asm volatile("s_waitcnt vmcnt(6)" ::: "memory");
        else            asm volatile("s_waitcnt vmcnt(0)" ::: "memory");
        __builtin_amdgcn_s_barrier();

        const int buf = t % 3;
        const unsigned lb = lbase + (unsigned)buf * 49152u;
        unsigned ab = lb + aoff, bb = lb + boff;
        unsigned ab1 = ab ^ 16u, bb1 = bb ^ 16u;

        u32x4 B0, B1, B2, B3, B4, B5, B6, B7;
        u32x4 A0, A4, A1v, A5, A2v, A6, A3, A7;
        // B frags + A row 0
        DSR(B0, bb, 0);    DSR(B1, bb, 2048);  DSR(B2, bb, 4096);  DSR(B3, bb, 6144);
        DSR(B4, bb1, 0);   DSR(B5, bb1, 2048); DSR(B6, bb1, 4096); DSR(B7, bb1, 6144);
        DSR(A0, ab, 0);    DSR(A4, ab1, 0);
        __builtin_amdgcn_sched_barrier(0);

        if (t + 2 < NT) STAGE(t + 2, (t + 2) % 3);
        __builtin_amdgcn_sched_barrier(0);

        // A row 1 in flight; wait for B + A0
        DSR(A1v, ab, 2048); DSR(A5, ab1, 2048);
        asm volatile("s_waitcnt lgkmcnt(2)" ::: "memory");
        __builtin_amdgcn_sched_barrier(0);

        s8v bh0, bl0, bh1, bl1, bh2, bl2, bh3, bl3;
        unpack8(B0, B4, bh0, bl0);
        unpack8(B1, B5, bh1, bl1);
        unpack8(B2, B6, bh2, bl2);
        unpack8(B3, B7, bh3, bl3);

        __builtin_amdgcn_s_setprio(1);
        {
            s8v ah, al;
            frag_a<AF32>(A0, A4, ah, al);
            TRI(ah, al, bh0, bl0, acc[0][0]) TRI(ah, al, bh1, bl1, acc[0][1])
            TRI(ah, al, bh2, bl2, acc[0][2]) TRI(ah, al, bh3, bl3, acc[0][3])
        }
        __builtin_amdgcn_sched_barrier(0);
        DSR(A2v, ab, 4096); DSR(A6, ab1, 4096);
        asm volatile("s_waitcnt lgkmcnt(2)" ::: "memory");
        __builtin_amdgcn_sched_barrier(0);
        {
            s8v ah, al;
            frag_a<AF32>(A1v, A5, ah, al);
            TRI(ah, al, bh0, bl0, acc[1][0]) TRI(ah, al, bh1, bl1, acc[1][1])
            TRI(ah, al, bh2, bl2, acc[1][2]) TRI(ah, al, bh3, bl3, acc[1][3])
        }
        __builtin_amdgcn_sched_barrier(0);
        DSR(A3, ab, 6144); DSR(A7, ab1, 6144);
        asm volatile("s_waitcnt lgkmcnt(2)" ::: "memory");
        __builtin_amdgcn_sched_barrier(0);
        {
            s8v ah, al;
            frag_a<AF32>(A2v, A6, ah, al);
            TRI(ah, al, bh0, bl0, acc[2][0]) TRI(ah, al, bh1, bl1, acc[2][1])
            TRI(ah, al, bh2, bl2, acc[2][2]) TRI(ah, al, bh3, bl3, acc[2][3])
        }
        asm volatile("s_waitcnt lgkmcnt(0)" ::: "memory");
        __builtin_amdgcn_sched_barrier(0);
        {
            s8v ah, al;
            frag_a<AF32>(A3, A7, ah, al);
            TRI(ah, al, bh0, bl0, acc[3][0]) TRI(ah, al, bh1, bl1, acc[3][1])
            TRI(ah, al, bh2, bl2, acc[3][2]) TRI(ah, al, bh3, bl3, acc[3][3])
        }
        __builtin_amdgcn_s_setprio(0);
    }

    // epilogue.  C frag: col = lane&15, row = (lane>>4)*4 + reg
    #pragma unroll
    for (int j = 0; j < 4; ++j) {
        int col = wn * 64 + 16 * j + li;
        float b = bias[(col < NB) ? col : 0];
        #pragma unroll
        for (int i = 0; i < 4; ++i) {
            int row0 = bm + wm * 64 + 16 * i + kq * 4;
            #pragma unroll
            for (int r = 0; r < 4; ++r) {
                float v = acc[i][j][r] + b;
                if constexpr (DOTANH) {
                    if (row0 + r < M && col < NB)
                        Cf[(size_t)(row0 + r) * NB + col] = tanhf(v);
                } else {
                    Cpk[(size_t)(row0 + r) * 256 + col] = pack_split(fmaxf(v, 0.f));
                }
            }
        }
    }
}

// ---------------- launch ----------------

extern "C" void kernel_launch(void* const* d_in, const int* in_sizes, int n_in,
                              void* d_out, int out_size, void* d_ws, size_t ws_size,
                              hipStream_t stream) {
    const float* feat = (const float*)d_in[0];
    const int* einfo = (const int*)d_in[1];
    const float* b1 = (const float*)d_in[3];
    const float* b2 = (const float*)d_in[5];
    const float* b3 = (const float*)d_in[7];
    const float* bl1 = (const float*)d_in[9];
    const float* blH = (const float*)d_in[12];
    const float* bl2 = (const float*)d_in[15];
    const float* bp1 = (const float*)d_in[18];
    const float* bp2 = (const float*)d_in[20];
    const float* bp3 = (const float*)d_in[22];

    const int IN_DIM = 512;
    const int N = in_sizes[0] / IN_DIM;   // 50000
    const int E = in_sizes[1] / 2;        // 400000
    const int* src = einfo;
    const int* dst = einfo + E;
    const int M_pad = ((N + 127) / 128) * 128;      // 50176
    const size_t PLANE_U = (size_t)M_pad * 256;

    unsigned* P0 = (unsigned*)d_ws;
    unsigned* P1 = P0 + PLANE_U;
    unsigned* P2 = P1 + PLANE_U;
    unsigned* wp = P2 + PLANE_U;

    // packed weight planes (concat for fused SAGE GEMMs), sizes in u32
    const int gsz[9] = {131072, 65536, 65536, 131072, 131072, 131072, 65536, 65536, 32768};
    unsigned* G[9];
    {
        unsigned* c = wp;
        for (int i = 0; i < 9; ++i) { G[i] = c; c += gsz[i]; }
        wp = c;
    }

    const int widx[12]   = {2, 4, 6, 8, 10, 11, 13, 14, 16, 17, 19, 21};
    const int wplane[12] = {0, 1, 2, 3, 3, 4, 4, 5, 5, 6, 7, 8};
    const int wstr[12]   = {512, 256, 256, 512, 512, 512, 512, 512, 512, 256, 256, 256};
    const int wkoff[12]  = {0, 0, 0, 0, 256, 0, 256, 0, 256, 0, 0, 0};
    const int wnsh[12]   = {8, 8, 8, 8, 8, 8, 8, 8, 8, 8, 8, 7};
    const int welem[12]  = {131072, 65536, 65536, 65536, 65536, 65536, 65536,
                            65536, 65536, 65536, 65536, 32768};

    PrepW pa;
    int acc_end = 0;
    for (int i = 0; i < 12; ++i) {
        pa.W[i] = (const float*)d_in[widx[i]];
        pa.D[i] = G[wplane[i]];
        pa.stride[i] = wstr[i];
        pa.koff[i] = wkoff[i];
        pa.nshift[i] = wnsh[i];
        acc_end += welem[i];
        pa.end[i] = acc_end;
    }

    // 16B-aligned int arrays
    int* ioff = (int*)wp;                     // N+1, padded
    int* icnt = ioff + ((N + 1 + 3) & ~3);
    int* icur = icnt + ((N + 3) & ~3);
    int* csr  = icur + ((N + 3) & ~3);
    int* bsum = csr + ((E + 3) & ~3);         // up to 64

    const int NBLK = (N + 1023) / 1024;       // 49

    // CSR build + weight prep
    hipMemsetAsync(icnt, 0, (size_t)N * sizeof(int), stream);
    hipMemsetAsync(icur, 0, (size_t)N * sizeof(int), stream);
    hist_kernel<<<(E + 255) / 256, 256, 0, stream>>>(dst, icnt, E);
    scan_part<<<NBLK, 256, 0, stream>>>(icnt, bsum, N);
    scan_top<<<1, 64, 0, stream>>>(bsum, NBLK);
    scan_final<<<NBLK, 256, 0, stream>>>(icnt, bsum, ioff, N, E);
    scatter_kernel<<<(E + 255) / 256, 256, 0, stream>>>(src, dst, icur, ioff, csr, E);
    prep_weights<<<(acc_end + 255) / 256, 256, 0, stream>>>(pa, acc_end);

    const int GB = M_pad / 128;   // 392 blocks
    const int GA = (N + 3) / 4;

    // stem
    gemm_pipe<16, 0, true, 256, false><<<GB, 512, 0, stream>>>(
        feat, nullptr, nullptr, G[0], b1, P0, nullptr, N);
    gemm_pipe<8, 0, false, 256, false><<<GB, 512, 0, stream>>>(
        nullptr, P0, nullptr, G[1], b2, P1, nullptr, N);
    gemm_pipe<8, 0, false, 256, false><<<GB, 512, 0, stream>>>(
        nullptr, P1, nullptr, G[2], b3, P0, nullptr, N);

    // SAGE 1: x = P0
    sage_aggr_pk<<<GA, 256, 0, stream>>>(P0, csr, ioff, P1, N);
    gemm_pipe<8, 8, false, 256, false><<<GB, 512, 0, stream>>>(
        nullptr, P1, P0, G[3], bl1, P2, nullptr, N);

    // SAGE 2: x = P2
    sage_aggr_pk<<<GA, 256, 0, stream>>>(P2, csr, ioff, P1, N);
    gemm_pipe<8, 8, false, 256, false><<<GB, 512, 0, stream>>>(
        nullptr, P1, P2, G[4], blH, P0, nullptr, N);

    // SAGE 3: x = P0
    sage_aggr_pk<<<GA, 256, 0, stream>>>(P0, csr, ioff, P1, N);
    gemm_pipe<8, 8, false, 256, false><<<GB, 512, 0, stream>>>(
        nullptr, P1, P0, G[5], bl2, P2, nullptr, N);

    // head
    gemm_pipe<8, 0, false, 256, false><<<GB, 512, 0, stream>>>(
        nullptr, P2, nullptr, G[6], bp1, P0, nullptr, N);
    gemm_pipe<8, 0, false, 256, false><<<GB, 512, 0, stream>>>(
        nullptr, P0, nullptr, G[7], bp2, P1, nullptr, N);
    gemm_pipe<8, 0, false, 128, true><<<GB, 512, 0, stream>>>(
        nullptr, P1, nullptr, G[8], bp3, nullptr, (float*)d_out, N);
}